// Round 16
// baseline (155.761 us; speedup 1.0000x reference)
//
#include <hip/hip_runtime.h>
#include <hip/hip_bf16.h>
#include <math.h>

// Problem dims (fixed by setup_inputs): B=4, N=4096, C=128, H=512, S=32
static constexpr int BB = 4;
static constexpr int NN = 4096;
static constexpr int CC = 128;
static constexpr int HH = 512;
static constexpr int SS = 32;
static constexpr float EPSF = 1e-5f;
static constexpr int NCELL = 1000;            // 10x10x10 per batch

typedef __bf16 bf16_t;
typedef bf16_t bf16x8 __attribute__((ext_vector_type(8)));
typedef float f32x4 __attribute__((ext_vector_type(4)));
typedef float f32x2 __attribute__((ext_vector_type(2)));

__device__ inline unsigned short f2bf(float f) {
    unsigned int u = __builtin_bit_cast(unsigned int, f);
    u += 0x7FFFu + ((u >> 16) & 1u);          // RNE
    return (unsigned short)(u >> 16);
}
__device__ inline float u2f(unsigned int u) {
    return __builtin_bit_cast(float, u);
}
__device__ inline int cell_of(float v) {
    int c = (int)(v * 10.0f);
    return c > 9 ? 9 : (c < 0 ? 0 : c);
}
// packed fp32 fma with scalar broadcast: D = a * {g,g} + c  (contracts to v_pk_fma_f32)
__device__ inline f32x2 pk_fma_b(f32x2 a, float g, f32x2 c) {
    const f32x2 gg = {g, g};
    return a * gg + c;
}

__device__ inline void gload_lds16(const void* g, void* l) {
    __builtin_amdgcn_global_load_lds(
        (const __attribute__((address_space(1))) unsigned int*)g,
        (__attribute__((address_space(3))) unsigned int*)l, 16, 0, 0);
}

// ---------------------------------------------------------------------------
// Fused prep + binning.  1024 threads, 149 blocks (unchanged, measured-good).
// ---------------------------------------------------------------------------
__global__ __launch_bounds__(1024)
void prep_bin_kernel(const float* __restrict__ Wn, const float* __restrict__ W1,
                     const float* __restrict__ W2,
                     const float* __restrict__ gn, const float* __restrict__ bnv,
                     const float* __restrict__ mn, const float* __restrict__ vn,
                     const float* __restrict__ xyz,
                     unsigned short* __restrict__ WnF, unsigned short* __restrict__ W1b,
                     unsigned short* __restrict__ W2b, float4* __restrict__ wfold,
                     int* __restrict__ starts, float4* __restrict__ spts)
{
    const int blk = blockIdx.x;
    const int t   = threadIdx.x;

    __shared__ int cur[1024];
    __shared__ int ls[1024];

    if (blk < 144) {
        const int i = blk * 1024 + t;             // < 147456 exactly
        if (i < 16384) {
            const int o = i >> 7, c = i & 127;
            WnF[i] = f2bf(Wn[o * 131 + 3 + c]);
        } else if (i < 81920) {
            W1b[i - 16384] = f2bf(W1[i - 16384]);
        } else {
            W2b[i - 81920] = f2bf(W2[i - 81920]);
        }
        return;
    }
    if (blk == 144) {
        if (t < CC) {
            const float sc = gn[t] / sqrtf(vn[t] + EPSF);
            wfold[t] = make_float4(sc * Wn[t * 131 + 0], sc * Wn[t * 131 + 1],
                                   sc * Wn[t * 131 + 2], bnv[t] - mn[t] * sc);
        }
        return;
    }

    // ---- binning for batch b
    const int b = blk - 145;
    cur[t] = 0;
    __syncthreads();

    int    cid[4];
    float4 pt[4];
    #pragma unroll
    for (int k = 0; k < 4; ++k) {
        const int n = k * 1024 + t;               // coalesced
        const float x = xyz[((size_t)b * NN + n) * 3 + 0];
        const float y = xyz[((size_t)b * NN + n) * 3 + 1];
        const float z = xyz[((size_t)b * NN + n) * 3 + 2];
        cid[k] = cell_of(z) * 100 + cell_of(y) * 10 + cell_of(x);
        pt[k]  = make_float4(x, y, z, __int_as_float(n));
        atomicAdd(&cur[cid[k]], 1);
    }
    __syncthreads();

    const int v = cur[t];
    ls[t] = v;
    __syncthreads();
    #pragma unroll
    for (int off = 1; off < 1024; off <<= 1) {
        const int add = (t >= off) ? ls[t - off] : 0;
        __syncthreads();
        ls[t] += add;
        __syncthreads();
    }
    const int ex = ls[t] - v;
    if (t < NCELL) starts[b * NCELL + t] = b * NN + ex;
    if (b == 0 && t == 0) starts[BB * NCELL] = BB * NN;
    __syncthreads();
    cur[t] = ex;
    __syncthreads();

    #pragma unroll
    for (int k = 0; k < 4; ++k) {
        const int pos = atomicAdd(&cur[cid[k]], 1);
        spts[(size_t)b * NN + pos] = pt[k];
    }
}

// ---------------------------------------------------------------------------
// Fused T-GEMM + ball query (unchanged, measured-good).
// ---------------------------------------------------------------------------
__global__ __launch_bounds__(256, 2)
void tgemm_bq_kernel(const float* __restrict__ feats, const unsigned short* __restrict__ WnF,
                     const float* __restrict__ gn, const float* __restrict__ vn,
                     unsigned short* __restrict__ Tb,
                     const float* __restrict__ xyz, const int* __restrict__ starts,
                     const float4* __restrict__ spts, int* __restrict__ idx)
{
    __shared__ char smem[(64 + 128) * 128];       // 24576 B

    if (blockIdx.x < 256) {
        // ================= T-GEMM tile =================
        char* sA = smem;
        char* sB = smem + 64 * 128;
        const int t    = threadIdx.x;
        const int lane = t & 63;
        const int w    = t >> 6;
        const int wm   = w >> 1;
        const int wn   = w & 1;
        const int m0   = blockIdx.x * 64;

        f32x4 acc[2][4];
        #pragma unroll
        for (int i = 0; i < 2; ++i)
            #pragma unroll
            for (int j = 0; j < 4; ++j) acc[i][j] = f32x4{0.f, 0.f, 0.f, 0.f};

        const char* Wb = (const char*)WnF;

        for (int kc = 0; kc < CC; kc += 64) {
            #pragma unroll
            for (int l = 0; l < 2; ++l) {
                const int q     = w * 2 + l;
                const int Lb    = q * 1024 + lane * 16;
                const int row   = Lb >> 7;
                const int inrow = Lb & 127;
                const int sw    = inrow ^ ((row & 7) << 4);
                const float* src = feats + (size_t)(m0 + row) * CC + kc + (sw >> 1);
                const float4 a0 = *(const float4*)(src);
                const float4 a1 = *(const float4*)(src + 4);
                uint4 pk;
                pk.x = (unsigned)f2bf(a0.x) | ((unsigned)f2bf(a0.y) << 16);
                pk.y = (unsigned)f2bf(a0.z) | ((unsigned)f2bf(a0.w) << 16);
                pk.z = (unsigned)f2bf(a1.x) | ((unsigned)f2bf(a1.y) << 16);
                pk.w = (unsigned)f2bf(a1.z) | ((unsigned)f2bf(a1.w) << 16);
                *(uint4*)(sA + Lb) = pk;
            }
            #pragma unroll
            for (int l = 0; l < 4; ++l) {
                const int q     = w * 4 + l;
                const int Lb    = q * 1024 + lane * 16;
                const int row   = Lb >> 7;
                const int inrow = Lb & 127;
                const char* src = Wb + (size_t)row * 256 + kc * 2 + (inrow ^ ((row & 7) << 4));
                gload_lds16(src, sB + q * 1024);
            }
            __syncthreads();

            #pragma unroll
            for (int ks = 0; ks < 2; ++ks) {
                const int kbyte = ks * 64 + (lane >> 4) * 16;
                bf16x8 af[2], bf[4];
                #pragma unroll
                for (int i = 0; i < 2; ++i) {
                    const int r = wm * 32 + i * 16 + (lane & 15);
                    af[i] = *(const bf16x8*)(sA + r * 128 + (kbyte ^ ((r & 7) << 4)));
                }
                #pragma unroll
                for (int j = 0; j < 4; ++j) {
                    const int r = wn * 64 + j * 16 + (lane & 15);
                    bf[j] = *(const bf16x8*)(sB + r * 128 + (kbyte ^ ((r & 7) << 4)));
                }
                #pragma unroll
                for (int i = 0; i < 2; ++i)
                    #pragma unroll
                    for (int j = 0; j < 4; ++j)
                        acc[i][j] = __builtin_amdgcn_mfma_f32_16x16x32_bf16(af[i], bf[j], acc[i][j], 0, 0, 0);
            }
            __syncthreads();
        }

        #pragma unroll
        for (int j = 0; j < 4; ++j) {
            const int col = wn * 64 + j * 16 + (lane & 15);
            const float scg = gn[col] / sqrtf(vn[col] + EPSF);
            #pragma unroll
            for (int i = 0; i < 2; ++i) {
                const int rowb = m0 + wm * 32 + i * 16 + (lane >> 4) * 4;
                #pragma unroll
                for (int r = 0; r < 4; ++r)
                    Tb[(size_t)(rowb + r) * CC + col] = f2bf(acc[i][j][r] * scg);
            }
        }
    } else {
        // ================= ball query (4 queries, 1 wave each) =================
        const int t    = threadIdx.x;
        const int wv   = t >> 6;
        const int lane = t & 63;
        const int p    = (blockIdx.x - 256) * 4 + wv;
        const int b    = p >> 12;

        int* lbase = (int*)smem + wv * 160;       // per-wave: list[128] + res[32]
        int* list  = lbase;
        int* res   = lbase + 128;

        const float qx = xyz[p * 3 + 0];
        const float qy = xyz[p * 3 + 1];
        const float qz = xyz[p * 3 + 2];
        const int cx = cell_of(qx), cy = cell_of(qy), cz = cell_of(qz);
        const int xlo = cx > 0 ? cx - 1 : 0;
        const int xhi = cx < 9 ? cx + 1 : 9;

        int cnt = 0;
        for (int dz = -1; dz <= 1; ++dz) {
            const int z2 = cz + dz;
            if (z2 < 0 || z2 > 9) continue;
            for (int dy = -1; dy <= 1; ++dy) {
                const int y2 = cy + dy;
                if (y2 < 0 || y2 > 9) continue;
                const int base = b * NCELL + z2 * 100 + y2 * 10;
                const int lo = starts[base + xlo];
                const int hi = starts[base + xhi + 1];
                for (int j0 = lo; j0 < hi; j0 += 64) {
                    const int j = j0 + lane;
                    bool in = false;
                    int pi = 0;
                    if (j < hi) {
                        const float4 s = spts[j];
                        float sq;
                        {
                            #pragma clang fp contract(off)   // match numpy at boundary
                            const float dx  = qx - s.x;
                            const float dyv = qy - s.y;
                            const float dzv = qz - s.z;
                            sq = dx * dx + dyv * dyv + dzv * dzv;
                        }
                        in = (sq <= 0.01f);
                        pi = __float_as_int(s.w);
                    }
                    const unsigned long long mask = __ballot(in);
                    if (in) {
                        const int pos = cnt + __popcll(mask & ((1ull << lane) - 1ull));
                        if (pos < 128) list[pos] = pi;
                    }
                    cnt += (int)__popcll(mask);
                }
            }
        }
        __syncthreads();                          // uniform: all 4 waves reach

        const int c = cnt < 128 ? cnt : 128;      // c >= 1 (self always in-radius)
        #pragma unroll
        for (int l0 = 0; l0 < 2; ++l0) {
            const int l = lane + l0 * 64;
            if (l < c) {
                const int v = list[l];
                int r = 0;
                for (int k = 0; k < c; ++k) r += (list[k] < v);
                if (r < SS) res[r] = v;
            }
        }
        __syncthreads();

        if (lane < SS) {
            const int m = c < SS ? c : SS;
            idx[(size_t)p * SS + lane] = (lane < m) ? res[lane] : res[0];
        }
    }
}

// ---------------------------------------------------------------------------
// Fused MLP tail: per block = 64 points (one batch).
//  Phase A: x-tile = relu(max_s(T'_gather + w'·g) + sh) -> swizzled LDS (xs)
//  Phase B: h-tile = relu(bn1(x @ W1^T)) -> LDS (hs, 64x512 bf16), W1 staged
//           in 32KB region reused from Phase A's sg buffer, 4 x 128-col chunks
//  Phase C: out = relu(bn2(h @ W2^T) + feats) -> fp32 global, W2 staged per
//           64-K chunk (8 iters)
// LDS: hs 64KB + multiuse 32KB + xs 16KB = 112KB -> 1 block/CU; grid = 256.
// ---------------------------------------------------------------------------
__global__ __launch_bounds__(256, 1)
void fused_mlp_kernel(const float* __restrict__ xyz,
                      const unsigned short* __restrict__ T,   // pre-scaled bf16
                      const float4* __restrict__ wfold,
                      const int* __restrict__ idx,
                      const unsigned short* __restrict__ W1b,
                      const float* __restrict__ g1, const float* __restrict__ b1,
                      const float* __restrict__ m1, const float* __restrict__ v1,
                      const unsigned short* __restrict__ W2b,
                      const float* __restrict__ g2, const float* __restrict__ b2,
                      const float* __restrict__ m2, const float* __restrict__ v2,
                      const float* __restrict__ feats, float* __restrict__ out)
{
    __shared__ char smem[114688];
    char* hs  = smem;                 // 64 x 512 bf16, 1024B rows, 64KB
    char* ws2 = smem + 65536;         // 32KB multiuse: sg (A) / W-stage (B,C)
    char* xs  = smem + 98304;         // 64 x 128 bf16, 256B rows, 16KB

    const int t    = threadIdx.x;
    const int m0   = blockIdx.x * 64;
    const int b    = m0 >> 12;        // 64 blocks per batch; no tile straddles
    const int lane = t & 63;
    const int w    = t >> 6;
    const int wm   = w >> 1;
    const int wn   = w & 1;

    // ================= Phase A: group-max into xs =================
    {
        float4* sg = (float4*)ws2;    // [64][32] {gx,gy,gz,bitcast(j)}
        const int ptl = t >> 5;       // 0..7
        const int l   = t & 31;

        #pragma unroll
        for (int kp = 0; kp < 8; ++kp) {
            const int pl = kp * 8 + ptl;
            const int p  = m0 + pl;
            const int j  = idx[(size_t)p * SS + l];
            const float* q  = xyz + (size_t)p * 3;
            const float* pj = xyz + ((size_t)b * NN + j) * 3;
            sg[pl * 32 + l] = make_float4((pj[0] - q[0]) / 0.1f,
                                          (pj[1] - q[1]) / 0.1f,
                                          (pj[2] - q[2]) / 0.1f, __int_as_float(j));
        }
        __syncthreads();

        const int c0 = l * 4;
        const float4 wa = wfold[c0 + 0], wb = wfold[c0 + 1];
        const float4 wc = wfold[c0 + 2], wd = wfold[c0 + 3];
        const f32x2 w0p0 = {wa.x, wb.x}, w1p0 = {wa.y, wb.y}, w2p0 = {wa.z, wb.z};
        const f32x2 w0p1 = {wc.x, wd.x}, w1p1 = {wc.y, wd.y}, w2p1 = {wc.z, wd.z};
        const unsigned short* Tbp = T + (size_t)b * NN * CC;

        for (int kp = 0; kp < 8; ++kp) {
            const int pl = kp * 8 + ptl;
            f32x2 mx0 = {-1e30f, -1e30f}, mx1 = {-1e30f, -1e30f};
            #pragma unroll 8
            for (int s = 0; s < SS; ++s) {
                const float4 g = sg[pl * 32 + s];
                const int j = __float_as_int(g.w);
                const uint2 tv = *(const uint2*)(Tbp + (size_t)j * CC + c0);
                f32x2 v0, v1;
                v0.x = u2f(tv.x << 16); v0.y = u2f(tv.x & 0xFFFF0000u);
                v1.x = u2f(tv.y << 16); v1.y = u2f(tv.y & 0xFFFF0000u);
                v0 = pk_fma_b(w0p0, g.x, v0); v0 = pk_fma_b(w1p0, g.y, v0); v0 = pk_fma_b(w2p0, g.z, v0);
                v1 = pk_fma_b(w0p1, g.x, v1); v1 = pk_fma_b(w1p1, g.y, v1); v1 = pk_fma_b(w2p1, g.z, v1);
                mx0.x = fmaxf(mx0.x, v0.x); mx0.y = fmaxf(mx0.y, v0.y);
                mx1.x = fmaxf(mx1.x, v1.x); mx1.y = fmaxf(mx1.y, v1.y);
            }
            const float r0 = fmaxf(mx0.x + wa.w, 0.f);
            const float r1 = fmaxf(mx0.y + wb.w, 0.f);
            const float r2 = fmaxf(mx1.x + wc.w, 0.f);
            const float r3 = fmaxf(mx1.y + wd.w, 0.f);
            uint2 o;
            o.x = (unsigned)f2bf(r0) | ((unsigned)f2bf(r1) << 16);
            o.y = (unsigned)f2bf(r2) | ((unsigned)f2bf(r3) << 16);
            // swizzled xs write (row = pl, 256B rows)
            *(uint2*)(xs + pl * 256 + ((c0 * 2) ^ ((pl & 7) << 4))) = o;
        }
    }
    __syncthreads();                  // xs ready; sg region free

    // ================= Phase B: h-tile into hs =================
    for (int nc = 0; nc < 4; ++nc) {
        // stage W1 chunk: rows nc*128..+128, all K (256B/row) -> 32KB
        #pragma unroll
        for (int lq = 0; lq < 8; ++lq) {
            const int Lb    = (lq * 256 + t) * 16;
            const int row   = Lb >> 8;
            const int inrow = Lb & 255;
            const int sw    = inrow ^ ((row & 7) << 4);
            gload_lds16((const char*)W1b + (size_t)(nc * 128 + row) * 256 + sw, ws2 + Lb);
        }
        __syncthreads();

        f32x4 acc[2][4];
        #pragma unroll
        for (int i = 0; i < 2; ++i)
            #pragma unroll
            for (int j = 0; j < 4; ++j) acc[i][j] = f32x4{0.f, 0.f, 0.f, 0.f};

        #pragma unroll
        for (int kc = 0; kc < 2; ++kc) {
            #pragma unroll
            for (int ks = 0; ks < 2; ++ks) {
                const int kbyte = kc * 128 + ks * 64 + (lane >> 4) * 16;
                bf16x8 af[2], bf[4];
                #pragma unroll
                for (int i = 0; i < 2; ++i) {
                    const int r = wm * 32 + i * 16 + (lane & 15);
                    af[i] = *(const bf16x8*)(xs + r * 256 + (kbyte ^ ((r & 7) << 4)));
                }
                #pragma unroll
                for (int j = 0; j < 4; ++j) {
                    const int r = wn * 64 + j * 16 + (lane & 15);
                    bf[j] = *(const bf16x8*)(ws2 + r * 256 + (kbyte ^ ((r & 7) << 4)));
                }
                #pragma unroll
                for (int i = 0; i < 2; ++i)
                    #pragma unroll
                    for (int j = 0; j < 4; ++j)
                        acc[i][j] = __builtin_amdgcn_mfma_f32_16x16x32_bf16(af[i], bf[j], acc[i][j], 0, 0, 0);
            }
        }

        // epilogue: bn1+relu -> hs (swizzled bf16, 1024B rows)
        #pragma unroll
        for (int j = 0; j < 4; ++j) {
            const int col = nc * 128 + wn * 64 + j * 16 + (lane & 15);
            const float scg = g1[col] / sqrtf(v1[col] + EPSF);
            const float mm  = m1[col];
            const float sh  = b1[col];
            #pragma unroll
            for (int i = 0; i < 2; ++i) {
                const int rowb = wm * 32 + i * 16 + (lane >> 4) * 4;
                #pragma unroll
                for (int r = 0; r < 4; ++r) {
                    const float z = fmaxf((acc[i][j][r] - mm) * scg + sh, 0.f);
                    const int row = rowb + r;
                    *(unsigned short*)(hs + row * 1024 + ((col * 2) ^ ((row & 7) << 4))) = f2bf(z);
                }
            }
        }
        __syncthreads();              // hs chunk visible; ws2 safe to restage
    }

    // ================= Phase C: out-GEMM (K=512) =================
    f32x4 acc2[2][4];
    #pragma unroll
    for (int i = 0; i < 2; ++i)
        #pragma unroll
        for (int j = 0; j < 4; ++j) acc2[i][j] = f32x4{0.f, 0.f, 0.f, 0.f};

    for (int kc = 0; kc < 8; ++kc) {
        // stage W2 chunk: 128 rows x 128B (K-range kc*64..+64) -> 16KB
        #pragma unroll
        for (int lq = 0; lq < 4; ++lq) {
            const int Lb    = (lq * 256 + t) * 16;
            const int row   = Lb >> 7;
            const int inrow = Lb & 127;
            const int sw    = inrow ^ ((row & 7) << 4);
            gload_lds16((const char*)W2b + (size_t)row * 1024 + kc * 128 + sw, ws2 + Lb);
        }
        __syncthreads();

        #pragma unroll
        for (int ks = 0; ks < 2; ++ks) {
            const int kb_hs = kc * 128 + ks * 64 + (lane >> 4) * 16;
            const int kb_w  = ks * 64 + (lane >> 4) * 16;
            bf16x8 af[2], bf[4];
            #pragma unroll
            for (int i = 0; i < 2; ++i) {
                const int r = wm * 32 + i * 16 + (lane & 15);
                af[i] = *(const bf16x8*)(hs + r * 1024 + (kb_hs ^ ((r & 7) << 4)));
            }
            #pragma unroll
            for (int j = 0; j < 4; ++j) {
                const int r = wn * 64 + j * 16 + (lane & 15);
                bf[j] = *(const bf16x8*)(ws2 + r * 128 + (kb_w ^ ((r & 7) << 4)));
            }
            #pragma unroll
            for (int i = 0; i < 2; ++i)
                #pragma unroll
                for (int j = 0; j < 4; ++j)
                    acc2[i][j] = __builtin_amdgcn_mfma_f32_16x16x32_bf16(af[i], bf[j], acc2[i][j], 0, 0, 0);
        }
        __syncthreads();              // done reading ws2 before restage
    }

    // epilogue: bn2 + residual + relu -> fp32 out
    #pragma unroll
    for (int j = 0; j < 4; ++j) {
        const int col = wn * 64 + j * 16 + (lane & 15);
        const float scg = g2[col] / sqrtf(v2[col] + EPSF);
        const float mm  = m2[col];
        const float sh  = b2[col];
        #pragma unroll
        for (int i = 0; i < 2; ++i) {
            const int rowb = m0 + wm * 32 + i * 16 + (lane >> 4) * 4;
            #pragma unroll
            for (int r = 0; r < 4; ++r) {
                float z = (acc2[i][j][r] - mm) * scg + sh;
                z += feats[(size_t)(rowb + r) * CC + col];
                out[(size_t)(rowb + r) * CC + col] = fmaxf(z, 0.f);
            }
        }
    }
}

// ---------------------------------------------------------------------------
extern "C" void kernel_launch(void* const* d_in, const int* in_sizes, int n_in,
                              void* d_out, int out_size, void* d_ws, size_t ws_size,
                              hipStream_t stream)
{
    const float* xyz   = (const float*)d_in[0];
    const float* feats = (const float*)d_in[1];
    const float* Wn    = (const float*)d_in[2];
    const float* gn    = (const float*)d_in[3];
    const float* bn_   = (const float*)d_in[4];
    const float* mn    = (const float*)d_in[5];
    const float* vn    = (const float*)d_in[6];
    const float* W1    = (const float*)d_in[7];
    const float* g1    = (const float*)d_in[8];
    const float* b1    = (const float*)d_in[9];
    const float* m1    = (const float*)d_in[10];
    const float* v1    = (const float*)d_in[11];
    const float* W2    = (const float*)d_in[12];
    const float* g2    = (const float*)d_in[13];
    const float* b2    = (const float*)d_in[14];
    const float* m2    = (const float*)d_in[15];
    const float* v2    = (const float*)d_in[16];
    float* out = (float*)d_out;

    // workspace layout (bytes, 256-aligned)
    char* ws = (char*)d_ws;
    int*            idx    = (int*)(ws);                        // 2 MB
    int*            starts = (int*)(ws + 2097152);              // 16 KB (4001 ints)
    float4*         spts   = (float4*)(ws + 2113536);           // 256 KB
    unsigned short* WnF    = (unsigned short*)(ws + 2375680);   // 32 KB
    unsigned short* W1b    = (unsigned short*)(ws + 2408448);   // 128 KB
    unsigned short* W2b    = (unsigned short*)(ws + 2539520);   // 128 KB
    unsigned short* Tb     = (unsigned short*)(ws + 2670592);   // 4 MB
    float4*         wfold  = (float4*)(ws + 6864896);           // 2 KB (~6.9 MB total)

    const int M = BB * NN;  // 16384

    // 1) weights pack + wfold + binning (fused)
    prep_bin_kernel<<<149, 1024, 0, stream>>>(Wn, W1, W2, gn, bn_, mn, vn, xyz,
                                              WnF, W1b, W2b, wfold, starts, spts);

    // 2) T' = sc1*(feats @ WnF^T) -> bf16   ∥   ball query (fused launch)
    tgemm_bq_kernel<<<256 + M / 4, 256, 0, stream>>>(feats, WnF, gn, vn, Tb,
                                                     xyz, starts, spts, idx);

    // 3) fused MLP tail: group-max + h-GEMM + out-GEMM (1 block / 64 points)
    fused_mlp_kernel<<<M / 64, 256, 0, stream>>>(xyz, Tb, wfold, idx,
                                                 W1b, g1, b1, m1, v1,
                                                 W2b, g2, b2, m2, v2,
                                                 feats, out);
}

// Round 17
// 152.999 us; speedup vs baseline: 1.0180x; 1.0180x over previous
//
#include <hip/hip_runtime.h>
#include <hip/hip_bf16.h>
#include <math.h>

// Problem dims (fixed by setup_inputs): B=4, N=4096, C=128, H=512, S=32
static constexpr int BB = 4;
static constexpr int NN = 4096;
static constexpr int CC = 128;
static constexpr int HH = 512;
static constexpr int SS = 32;
static constexpr float EPSF = 1e-5f;
static constexpr int NCELL = 1000;            // 10x10x10 per batch

typedef __bf16 bf16_t;
typedef bf16_t bf16x8 __attribute__((ext_vector_type(8)));
typedef float f32x4 __attribute__((ext_vector_type(4)));
typedef float f32x2 __attribute__((ext_vector_type(2)));

__device__ inline unsigned short f2bf(float f) {
    unsigned int u = __builtin_bit_cast(unsigned int, f);
    u += 0x7FFFu + ((u >> 16) & 1u);          // RNE
    return (unsigned short)(u >> 16);
}
__device__ inline float u2f(unsigned int u) {
    return __builtin_bit_cast(float, u);
}
__device__ inline int cell_of(float v) {
    int c = (int)(v * 10.0f);
    return c > 9 ? 9 : (c < 0 ? 0 : c);
}
// packed fp32 fma with scalar broadcast: D = a * {g,g} + c  (contracts to v_pk_fma_f32)
__device__ inline f32x2 pk_fma_b(f32x2 a, float g, f32x2 c) {
    const f32x2 gg = {g, g};
    return a * gg + c;
}

__device__ inline void gload_lds16(const void* g, void* l) {
    __builtin_amdgcn_global_load_lds(
        (const __attribute__((address_space(1))) unsigned int*)g,
        (__attribute__((address_space(3))) unsigned int*)l, 16, 0, 0);
}

// ---------------------------------------------------------------------------
// Fused prep + binning.  1024 threads, 149 blocks (measured-good, round 14).
// ---------------------------------------------------------------------------
__global__ __launch_bounds__(1024)
void prep_bin_kernel(const float* __restrict__ Wn, const float* __restrict__ W1,
                     const float* __restrict__ W2,
                     const float* __restrict__ gn, const float* __restrict__ bnv,
                     const float* __restrict__ mn, const float* __restrict__ vn,
                     const float* __restrict__ xyz,
                     unsigned short* __restrict__ WnF, unsigned short* __restrict__ W1b,
                     unsigned short* __restrict__ W2b, float4* __restrict__ wfold,
                     int* __restrict__ starts, float4* __restrict__ spts)
{
    const int blk = blockIdx.x;
    const int t   = threadIdx.x;

    __shared__ int cur[1024];
    __shared__ int ls[1024];

    if (blk < 144) {
        const int i = blk * 1024 + t;             // < 147456 exactly
        if (i < 16384) {
            const int o = i >> 7, c = i & 127;
            WnF[i] = f2bf(Wn[o * 131 + 3 + c]);
        } else if (i < 81920) {
            W1b[i - 16384] = f2bf(W1[i - 16384]);
        } else {
            W2b[i - 81920] = f2bf(W2[i - 81920]);
        }
        return;
    }
    if (blk == 144) {
        // wfold[o] = {sc*w0, sc*w1, sc*w2, sh}
        if (t < CC) {
            const float sc = gn[t] / sqrtf(vn[t] + EPSF);
            wfold[t] = make_float4(sc * Wn[t * 131 + 0], sc * Wn[t * 131 + 1],
                                   sc * Wn[t * 131 + 2], bnv[t] - mn[t] * sc);
        }
        return;
    }

    // ---- binning for batch b
    const int b = blk - 145;
    cur[t] = 0;
    __syncthreads();

    int    cid[4];
    float4 pt[4];
    #pragma unroll
    for (int k = 0; k < 4; ++k) {
        const int n = k * 1024 + t;               // coalesced
        const float x = xyz[((size_t)b * NN + n) * 3 + 0];
        const float y = xyz[((size_t)b * NN + n) * 3 + 1];
        const float z = xyz[((size_t)b * NN + n) * 3 + 2];
        cid[k] = cell_of(z) * 100 + cell_of(y) * 10 + cell_of(x);
        pt[k]  = make_float4(x, y, z, __int_as_float(n));
        atomicAdd(&cur[cid[k]], 1);
    }
    __syncthreads();

    const int v = cur[t];
    ls[t] = v;
    __syncthreads();
    #pragma unroll
    for (int off = 1; off < 1024; off <<= 1) {
        const int add = (t >= off) ? ls[t - off] : 0;
        __syncthreads();
        ls[t] += add;
        __syncthreads();
    }
    const int ex = ls[t] - v;                     // exclusive prefix (cell t)
    if (t < NCELL) starts[b * NCELL + t] = b * NN + ex;
    if (b == 0 && t == 0) starts[BB * NCELL] = BB * NN;
    __syncthreads();
    cur[t] = ex;
    __syncthreads();

    #pragma unroll
    for (int k = 0; k < 4; ++k) {
        const int pos = atomicAdd(&cur[cid[k]], 1);
        spts[(size_t)b * NN + pos] = pt[k];
    }
}

// ---------------------------------------------------------------------------
// Fused T-GEMM + ball query.  256 threads.
//   blocks [0,256)    : T' = sc1*(feats @ WnF^T) tile (BM=64, BN=128, K=128)
//   blocks [256,4352) : binned ball query, 4 queries/block (1 wave each).
// Change vs round 14: bq waves no longer __syncthreads-joined — each wave
// only touches its OWN list/res LDS slice, and within-wave LDS write->read
// ordering is guaranteed by compiler lgkmcnt waits. Decouples slowest wave.
// ---------------------------------------------------------------------------
__global__ __launch_bounds__(256, 2)
void tgemm_bq_kernel(const float* __restrict__ feats, const unsigned short* __restrict__ WnF,
                     const float* __restrict__ gn, const float* __restrict__ vn,
                     unsigned short* __restrict__ Tb,
                     const float* __restrict__ xyz, const int* __restrict__ starts,
                     const float4* __restrict__ spts, int* __restrict__ idx)
{
    __shared__ char smem[(64 + 128) * 128];       // 24576 B

    if (blockIdx.x < 256) {
        // ================= T-GEMM tile =================
        char* sA = smem;
        char* sB = smem + 64 * 128;
        const int t    = threadIdx.x;
        const int lane = t & 63;
        const int w    = t >> 6;
        const int wm   = w >> 1;
        const int wn   = w & 1;
        const int m0   = blockIdx.x * 64;

        f32x4 acc[2][4];
        #pragma unroll
        for (int i = 0; i < 2; ++i)
            #pragma unroll
            for (int j = 0; j < 4; ++j) acc[i][j] = f32x4{0.f, 0.f, 0.f, 0.f};

        const char* Wb = (const char*)WnF;

        for (int kc = 0; kc < CC; kc += 64) {
            #pragma unroll
            for (int l = 0; l < 2; ++l) {
                const int q     = w * 2 + l;
                const int Lb    = q * 1024 + lane * 16;
                const int row   = Lb >> 7;
                const int inrow = Lb & 127;
                const int sw    = inrow ^ ((row & 7) << 4);
                const float* src = feats + (size_t)(m0 + row) * CC + kc + (sw >> 1);
                const float4 a0 = *(const float4*)(src);
                const float4 a1 = *(const float4*)(src + 4);
                uint4 pk;
                pk.x = (unsigned)f2bf(a0.x) | ((unsigned)f2bf(a0.y) << 16);
                pk.y = (unsigned)f2bf(a0.z) | ((unsigned)f2bf(a0.w) << 16);
                pk.z = (unsigned)f2bf(a1.x) | ((unsigned)f2bf(a1.y) << 16);
                pk.w = (unsigned)f2bf(a1.z) | ((unsigned)f2bf(a1.w) << 16);
                *(uint4*)(sA + Lb) = pk;
            }
            #pragma unroll
            for (int l = 0; l < 4; ++l) {
                const int q     = w * 4 + l;
                const int Lb    = q * 1024 + lane * 16;
                const int row   = Lb >> 7;
                const int inrow = Lb & 127;
                const char* src = Wb + (size_t)row * 256 + kc * 2 + (inrow ^ ((row & 7) << 4));
                gload_lds16(src, sB + q * 1024);
            }
            __syncthreads();

            #pragma unroll
            for (int ks = 0; ks < 2; ++ks) {
                const int kbyte = ks * 64 + (lane >> 4) * 16;
                bf16x8 af[2], bf[4];
                #pragma unroll
                for (int i = 0; i < 2; ++i) {
                    const int r = wm * 32 + i * 16 + (lane & 15);
                    af[i] = *(const bf16x8*)(sA + r * 128 + (kbyte ^ ((r & 7) << 4)));
                }
                #pragma unroll
                for (int j = 0; j < 4; ++j) {
                    const int r = wn * 64 + j * 16 + (lane & 15);
                    bf[j] = *(const bf16x8*)(sB + r * 128 + (kbyte ^ ((r & 7) << 4)));
                }
                #pragma unroll
                for (int i = 0; i < 2; ++i)
                    #pragma unroll
                    for (int j = 0; j < 4; ++j)
                        acc[i][j] = __builtin_amdgcn_mfma_f32_16x16x32_bf16(af[i], bf[j], acc[i][j], 0, 0, 0);
            }
            __syncthreads();
        }

        #pragma unroll
        for (int j = 0; j < 4; ++j) {
            const int col = wn * 64 + j * 16 + (lane & 15);
            const float scg = gn[col] / sqrtf(vn[col] + EPSF);
            #pragma unroll
            for (int i = 0; i < 2; ++i) {
                const int rowb = m0 + wm * 32 + i * 16 + (lane >> 4) * 4;
                #pragma unroll
                for (int r = 0; r < 4; ++r)
                    Tb[(size_t)(rowb + r) * CC + col] = f2bf(acc[i][j][r] * scg);
            }
        }
    } else {
        // ================= ball query (4 queries, 1 wave each) =================
        const int t    = threadIdx.x;
        const int wv   = t >> 6;
        const int lane = t & 63;
        const int p    = (blockIdx.x - 256) * 4 + wv;
        const int b    = p >> 12;

        int* lbase = (int*)smem + wv * 160;       // per-wave: list[128] + res[32]
        int* list  = lbase;
        int* res   = lbase + 128;

        const float qx = xyz[p * 3 + 0];
        const float qy = xyz[p * 3 + 1];
        const float qz = xyz[p * 3 + 2];
        const int cx = cell_of(qx), cy = cell_of(qy), cz = cell_of(qz);
        const int xlo = cx > 0 ? cx - 1 : 0;
        const int xhi = cx < 9 ? cx + 1 : 9;

        int cnt = 0;
        for (int dz = -1; dz <= 1; ++dz) {
            const int z2 = cz + dz;
            if (z2 < 0 || z2 > 9) continue;
            for (int dy = -1; dy <= 1; ++dy) {
                const int y2 = cy + dy;
                if (y2 < 0 || y2 > 9) continue;
                const int base = b * NCELL + z2 * 100 + y2 * 10;
                const int lo = starts[base + xlo];
                const int hi = starts[base + xhi + 1];
                for (int j0 = lo; j0 < hi; j0 += 64) {
                    const int j = j0 + lane;
                    bool in = false;
                    int pi = 0;
                    if (j < hi) {
                        const float4 s = spts[j];
                        float sq;
                        {
                            #pragma clang fp contract(off)   // match numpy at boundary
                            const float dx  = qx - s.x;
                            const float dyv = qy - s.y;
                            const float dzv = qz - s.z;
                            sq = dx * dx + dyv * dyv + dzv * dzv;
                        }
                        in = (sq <= 0.01f);
                        pi = __float_as_int(s.w);
                    }
                    const unsigned long long mask = __ballot(in);
                    if (in) {
                        const int pos = cnt + __popcll(mask & ((1ull << lane) - 1ull));
                        if (pos < 128) list[pos] = pi;
                    }
                    cnt += (int)__popcll(mask);
                }
            }
        }
        // no __syncthreads: per-wave LDS only; lgkmcnt orders within the wave

        const int c = cnt < 128 ? cnt : 128;      // c >= 1 (self always in-radius)
        #pragma unroll
        for (int l0 = 0; l0 < 2; ++l0) {
            const int l = lane + l0 * 64;
            if (l < c) {
                const int v = list[l];
                int r = 0;
                for (int k = 0; k < c; ++k) r += (list[k] < v);
                if (r < SS) res[r] = v;
            }
        }

        if (lane < SS) {
            const int m = c < SS ? c : SS;
            idx[(size_t)p * SS + lane] = (lane < m) ? res[lane] : res[0];
        }
    }
}

// ---------------------------------------------------------------------------
// Stage 1 fused: x[p,o] = relu( max_s ( T'[j_s,o] + w'[o]·gxyz_s ) + sh[o] )
// Block 256 thr = 8 points; 32 lanes/point, 4 channels/thread, packed fp32 fma.
// ---------------------------------------------------------------------------
__global__ __launch_bounds__(256)
void group_max_kernel(const float* __restrict__ xyz,
                      const unsigned short* __restrict__ T,   // pre-scaled bf16
                      const float4* __restrict__ wfold,
                      const int* __restrict__ idx, unsigned short* __restrict__ xout)
{
    const int t   = threadIdx.x;
    const int ptl = t >> 5;                    // 0..7 local point
    const int l   = t & 31;                    // lane within point
    const int p   = blockIdx.x * 8 + ptl;
    const int b   = p >> 12;

    __shared__ float4 sg[8][32];               // {gx, gy, gz, bitcast(j)}

    {
        const int j = idx[(size_t)p * SS + l];
        const float* q  = xyz + (size_t)p * 3;
        const float* pj = xyz + ((size_t)b * NN + j) * 3;
        sg[ptl][l] = make_float4((pj[0] - q[0]) / 0.1f,
                                 (pj[1] - q[1]) / 0.1f,
                                 (pj[2] - q[2]) / 0.1f, __int_as_float(j));
    }
    __syncthreads();

    const int c0 = l * 4;                      // this thread's 4 channels
    const float4 wa = wfold[c0 + 0], wb = wfold[c0 + 1];
    const float4 wc = wfold[c0 + 2], wd = wfold[c0 + 3];
    const f32x2 w0p0 = {wa.x, wb.x}, w1p0 = {wa.y, wb.y}, w2p0 = {wa.z, wb.z};
    const f32x2 w0p1 = {wc.x, wd.x}, w1p1 = {wc.y, wd.y}, w2p1 = {wc.z, wd.z};

    const unsigned short* Tbp = T + (size_t)b * NN * CC;
    f32x2 mx0 = {-1e30f, -1e30f}, mx1 = {-1e30f, -1e30f};

    #pragma unroll 8
    for (int s = 0; s < SS; ++s) {
        const float4 g = sg[ptl][s];
        const int j = __float_as_int(g.w);
        const uint2 tv = *(const uint2*)(Tbp + (size_t)j * CC + c0);
        f32x2 v0, v1;
        v0.x = u2f(tv.x << 16); v0.y = u2f(tv.x & 0xFFFF0000u);
        v1.x = u2f(tv.y << 16); v1.y = u2f(tv.y & 0xFFFF0000u);
        v0 = pk_fma_b(w0p0, g.x, v0); v0 = pk_fma_b(w1p0, g.y, v0); v0 = pk_fma_b(w2p0, g.z, v0);
        v1 = pk_fma_b(w0p1, g.x, v1); v1 = pk_fma_b(w1p1, g.y, v1); v1 = pk_fma_b(w2p1, g.z, v1);
        mx0.x = fmaxf(mx0.x, v0.x); mx0.y = fmaxf(mx0.y, v0.y);
        mx1.x = fmaxf(mx1.x, v1.x); mx1.y = fmaxf(mx1.y, v1.y);
    }

    const float r0 = fmaxf(mx0.x + wa.w, 0.f);
    const float r1 = fmaxf(mx0.y + wb.w, 0.f);
    const float r2 = fmaxf(mx1.x + wc.w, 0.f);
    const float r3 = fmaxf(mx1.y + wd.w, 0.f);
    uint2 o;
    o.x = (unsigned)f2bf(r0) | ((unsigned)f2bf(r1) << 16);
    o.y = (unsigned)f2bf(r2) | ((unsigned)f2bf(r3) << 16);
    *(uint2*)(xout + (size_t)p * CC + c0) = o;
}

// ---------------------------------------------------------------------------
// bf16 MFMA GEMM (B^T): BM=64, BNt in {64,128}, BK=64; 4 waves (2 x 2).
// MODE 1: bf16 relu(bn); MODE 2: f32 relu(bn + res).
// ---------------------------------------------------------------------------
template<int MODE, int BNt>
__global__ __launch_bounds__(256, 2)
void mfma_gemm_kernel(const unsigned short* __restrict__ A, const unsigned short* __restrict__ W,
                      const float* __restrict__ g, const float* __restrict__ bb,
                      const float* __restrict__ mu, const float* __restrict__ var,
                      const float* __restrict__ res, void* __restrict__ outv,
                      int M, int Nout, int K)
{
    constexpr int BM = 64, BK = 64;
    constexpr int NF = BNt / 32;               // n-frags per wave
    __shared__ char smem[(BM + BNt) * BK * 2];
    char* sA = smem;
    char* sB = smem + BM * BK * 2;

    const int t    = threadIdx.x;
    const int lane = t & 63;
    const int w    = t >> 6;
    const int wm   = w >> 1;
    const int wn   = w & 1;
    const int m0   = blockIdx.x * BM;
    const int o0   = blockIdx.y * BNt;
    const int Kb   = K * 2;

    f32x4 acc[2][NF];
    #pragma unroll
    for (int i = 0; i < 2; ++i)
        #pragma unroll
        for (int j = 0; j < NF; ++j) acc[i][j] = f32x4{0.f, 0.f, 0.f, 0.f};

    const char* Ab = (const char*)A;
    const char* Wb = (const char*)W;

    for (int kc = 0; kc < K; kc += BK) {
        const int kcb = kc * 2;
        #pragma unroll
        for (int l = 0; l < 2; ++l) {
            const int q     = w * 2 + l;
            const int Lb    = q * 1024 + lane * 16;
            const int row   = Lb >> 7;
            const int inrow = Lb & 127;
            const char* src = Ab + (size_t)(m0 + row) * Kb + kcb + (inrow ^ ((row & 7) << 4));
            gload_lds16(src, sA + q * 1024);
        }
        #pragma unroll
        for (int l = 0; l < NF; ++l) {
            const int q     = w * NF + l;
            const int Lb    = q * 1024 + lane * 16;
            const int row   = Lb >> 7;
            const int inrow = Lb & 127;
            const char* src = Wb + (size_t)(o0 + row) * Kb + kcb + (inrow ^ ((row & 7) << 4));
            gload_lds16(src, sB + q * 1024);
        }
        __syncthreads();

        #pragma unroll
        for (int ks = 0; ks < 2; ++ks) {
            const int kbyte = ks * 64 + (lane >> 4) * 16;
            bf16x8 af[2], bf[NF];
            #pragma unroll
            for (int i = 0; i < 2; ++i) {
                const int r = wm * 32 + i * 16 + (lane & 15);
                af[i] = *(const bf16x8*)(sA + r * 128 + (kbyte ^ ((r & 7) << 4)));
            }
            #pragma unroll
            for (int j = 0; j < NF; ++j) {
                const int r = wn * (BNt / 2) + j * 16 + (lane & 15);
                bf[j] = *(const bf16x8*)(sB + r * 128 + (kbyte ^ ((r & 7) << 4)));
            }
            #pragma unroll
            for (int i = 0; i < 2; ++i)
                #pragma unroll
                for (int j = 0; j < NF; ++j)
                    acc[i][j] = __builtin_amdgcn_mfma_f32_16x16x32_bf16(af[i], bf[j], acc[i][j], 0, 0, 0);
        }
        __syncthreads();
    }

    #pragma unroll
    for (int j = 0; j < NF; ++j) {
        const int col = o0 + wn * (BNt / 2) + j * 16 + (lane & 15);
        const float scg = g[col] / sqrtf(var[col] + EPSF);
        const float mm  = mu[col];
        const float sh  = bb[col];
        #pragma unroll
        for (int i = 0; i < 2; ++i) {
            const int rowb = m0 + wm * 32 + i * 16 + (lane >> 4) * 4;
            #pragma unroll
            for (int r = 0; r < 4; ++r) {
                float z = acc[i][j][r];
                z = (z - mm) * scg + sh;
                if constexpr (MODE == 2) z += res[(size_t)(rowb + r) * Nout + col];
                z = fmaxf(z, 0.f);
                if constexpr (MODE == 2)
                    ((float*)outv)[(size_t)(rowb + r) * Nout + col] = z;
                else
                    ((unsigned short*)outv)[(size_t)(rowb + r) * Nout + col] = f2bf(z);
            }
        }
    }
}

// ---------------------------------------------------------------------------
extern "C" void kernel_launch(void* const* d_in, const int* in_sizes, int n_in,
                              void* d_out, int out_size, void* d_ws, size_t ws_size,
                              hipStream_t stream)
{
    const float* xyz   = (const float*)d_in[0];
    const float* feats = (const float*)d_in[1];
    const float* Wn    = (const float*)d_in[2];
    const float* gn    = (const float*)d_in[3];
    const float* bn_   = (const float*)d_in[4];
    const float* mn    = (const float*)d_in[5];
    const float* vn    = (const float*)d_in[6];
    const float* W1    = (const float*)d_in[7];
    const float* g1    = (const float*)d_in[8];
    const float* b1    = (const float*)d_in[9];
    const float* m1    = (const float*)d_in[10];
    const float* v1    = (const float*)d_in[11];
    const float* W2    = (const float*)d_in[12];
    const float* g2    = (const float*)d_in[13];
    const float* b2    = (const float*)d_in[14];
    const float* m2    = (const float*)d_in[15];
    const float* v2    = (const float*)d_in[16];
    float* out = (float*)d_out;

    // workspace layout (bytes, 256-aligned)
    char* ws = (char*)d_ws;
    int*            idx    = (int*)(ws);                        // 2 MB
    int*            starts = (int*)(ws + 2097152);              // 16 KB (4001 ints)
    float4*         spts   = (float4*)(ws + 2113536);           // 256 KB
    unsigned short* WnF    = (unsigned short*)(ws + 2375680);   // 32 KB
    unsigned short* W1b    = (unsigned short*)(ws + 2408448);   // 128 KB
    unsigned short* W2b    = (unsigned short*)(ws + 2539520);   // 128 KB
    unsigned short* Tb     = (unsigned short*)(ws + 2670592);   // 4 MB
    unsigned short* xb     = (unsigned short*)(ws + 6864896);   // 4 MB
    unsigned short* hb     = (unsigned short*)(ws + 11059200);  // 16 MB
    float4*         wfold  = (float4*)(ws + 27836416);          // 2 KB (~27.8 MB total)

    const int M = BB * NN;  // 16384

    // 1) weights pack + wfold + binning (fused)
    prep_bin_kernel<<<149, 1024, 0, stream>>>(Wn, W1, W2, gn, bn_, mn, vn, xyz,
                                              WnF, W1b, W2b, wfold, starts, spts);

    // 2) T' = sc1*(feats @ WnF^T) -> bf16   ∥   ball query (fused launch)
    tgemm_bq_kernel<<<256 + M / 4, 256, 0, stream>>>(feats, WnF, gn, vn, Tb,
                                                     xyz, starts, spts, idx);

    // 3) x = relu(max_s (T'_gather + w'·g) + sh) -> bf16
    group_max_kernel<<<M / 8, 256, 0, stream>>>(xyz, Tb, wfold, idx, xb);

    // 4) h = relu(bn(x @ W1^T))   (M x 512, K=128) -> bf16
    mfma_gemm_kernel<1, 128><<<dim3(M / 64, HH / 128), 256, 0, stream>>>(
        xb, W1b, g1, b1, m1, v1, nullptr, hb, M, HH, CC);

    // 5) out = relu(bn(h @ W2^T) + feats)   (M x 128, K=512) -> f32
    mfma_gemm_kernel<2, 64><<<dim3(M / 64, CC / 64), 256, 0, stream>>>(
        hb, W2b, g2, b2, m2, v2, feats, out, M, CC, HH);
}